// Round 1
// baseline (959.093 us; speedup 1.0000x reference)
//
#include <hip/hip_runtime.h>

#define HH 128
#define WW 128
#define CC 128
#define BN 32
#define EPS 1e-5f
// NHW = 32*128*128 = 524288

// ---------------- Kernel 1: per-channel sum ----------------
__global__ __launch_bounds__(256) void k_sum(const float* __restrict__ x,
                                             float* __restrict__ sums, int n4) {
    __shared__ float s[128];
    int t = threadIdx.x;
    if (t < 128) s[t] = 0.0f;
    __syncthreads();
    long tid = (long)blockIdx.x * 256 + t;
    long stride = (long)gridDim.x * 256;
    const float4* x4 = (const float4*)x;
    float a0 = 0.f, a1 = 0.f, a2 = 0.f, a3 = 0.f;
    for (long i = tid; i < n4; i += stride) {
        float4 v = x4[i];
        a0 += v.x; a1 += v.y; a2 += v.z; a3 += v.w;
    }
    int c4 = (int)((tid * 4) & 127);
    atomicAdd(&s[c4 + 0], a0);
    atomicAdd(&s[c4 + 1], a1);
    atomicAdd(&s[c4 + 2], a2);
    atomicAdd(&s[c4 + 3], a3);
    __syncthreads();
    if (t < 128) atomicAdd(&sums[t], s[t]);
}

// ---------------- Kernel 2: per-channel sum of |x - mean| ----------------
__global__ __launch_bounds__(256) void k_abssum(const float* __restrict__ x,
                                                const float* __restrict__ sums,
                                                float* __restrict__ asums, int n4) {
    __shared__ float s[128];
    int t = threadIdx.x;
    if (t < 128) s[t] = 0.0f;
    __syncthreads();
    long tid = (long)blockIdx.x * 256 + t;
    long stride = (long)gridDim.x * 256;
    int c4 = (int)((tid * 4) & 127);
    const float invNHW = 1.0f / 524288.0f;
    float m0 = sums[c4 + 0] * invNHW;
    float m1 = sums[c4 + 1] * invNHW;
    float m2 = sums[c4 + 2] * invNHW;
    float m3 = sums[c4 + 3] * invNHW;
    const float4* x4 = (const float4*)x;
    float a0 = 0.f, a1 = 0.f, a2 = 0.f, a3 = 0.f;
    for (long i = tid; i < n4; i += stride) {
        float4 v = x4[i];
        a0 += fabsf(v.x - m0); a1 += fabsf(v.y - m1);
        a2 += fabsf(v.z - m2); a3 += fabsf(v.w - m3);
    }
    atomicAdd(&s[c4 + 0], a0);
    atomicAdd(&s[c4 + 1], a1);
    atomicAdd(&s[c4 + 2], a2);
    atomicAdd(&s[c4 + 3], a3);
    __syncthreads();
    if (t < 128) atomicAdd(&asums[t], s[t]);
}

// ---------------- Kernel 3: fused local+batch normalization ----------------
// Tile: 16x16 pixels x 8 channels per block. Halo: 4 before, 6 after per dim.
// xs:  26x26x8 staged x (zeros outside image)
// rs:  21x26x8 vertical 6-sums of x   (rows r -> global q_h = h0-2+r)
// lmd: 21x21x8 deviation field d = |x - local_mean| (0 outside image)
// rsd: 16x21x8 vertical 6-sums of d   (rows -> output row h0+r)
__global__ __launch_bounds__(256) void k_fused(const float* __restrict__ x,
                                               const float* __restrict__ sums,
                                               const float* __restrict__ asums,
                                               const float* __restrict__ gamma,
                                               const float* __restrict__ beta,
                                               const float* __restrict__ lbw,
                                               float* __restrict__ out) {
    __shared__ __align__(16) float xs[26 * 26 * 8];
    __shared__ __align__(16) float rs[21 * 26 * 8];
    __shared__ __align__(16) float lmd[21 * 21 * 8];
    __shared__ __align__(16) float rsd[16 * 21 * 8];
    __shared__ float prm[40];

    const int t = threadIdx.x;
    const int bx = blockIdx.x;
    const int n = blockIdx.y;
    const int c0 = (bx & 15) * 8;      // channel chunk fastest -> L2 line sharing
    const int tile = bx >> 4;
    const int h0 = (tile >> 3) * 16;
    const int w0 = (tile & 7) * 16;

    if (t < 8) {
        const float invNHW = 1.0f / 524288.0f;
        int c = c0 + t;
        prm[t]      = sums[c] * invNHW;                      // batch mean
        prm[8 + t]  = 1.0f / (asums[c] * invNHW + EPS);      // 1/(sigma+eps)
        prm[16 + t] = lbw[c];
        prm[24 + t] = gamma[c];
        prm[32 + t] = beta[c];
    }

    const int half = t & 1;
    const int coff = half * 4;
    const int pix = t >> 1;   // 0..127

    // Phase 1: stage x tile (float4 per lane; zeros for out-of-image)
    for (int p = pix; p < 676; p += 128) {
        int hh = p / 26, ww = p - hh * 26;
        int h = h0 - 4 + hh, w = w0 - 4 + ww;
        float4 v = make_float4(0.f, 0.f, 0.f, 0.f);
        if ((unsigned)h < 128u && (unsigned)w < 128u) {
            v = *(const float4*)&x[(((n * HH + h) * WW + w) * CC) + c0 + coff];
        }
        *(float4*)&xs[(hh * 26 + ww) * 8 + coff] = v;
    }
    __syncthreads();

    // Phase 2: vertical 6-sums of x
    for (int p = pix; p < 546; p += 128) {
        int r = p / 26, w = p - r * 26;
        float4 a = make_float4(0.f, 0.f, 0.f, 0.f);
        int base = (r * 26 + w) * 8 + coff;
        #pragma unroll
        for (int j = 0; j < 6; ++j) {
            float4 v = *(const float4*)&xs[base + j * (26 * 8)];
            a.x += v.x; a.y += v.y; a.z += v.z; a.w += v.w;
        }
        *(float4*)&rs[(r * 26 + w) * 8 + coff] = a;
    }
    __syncthreads();

    // Phase 3: local mean + deviation field d
    for (int p = pix; p < 441; p += 128) {
        int r = p / 21, q = p - r * 21;
        int qh = h0 - 2 + r, qw = w0 - 2 + q;
        float4 d = make_float4(0.f, 0.f, 0.f, 0.f);
        if ((unsigned)qh < 128u && (unsigned)qw < 128u) {
            int lo_h = max(qh - 2, 0), hi_h = min(qh + 3, 127);
            int lo_w = max(qw - 2, 0), hi_w = min(qw + 3, 127);
            float inv_cnt = 1.0f / (float)((hi_h - lo_h + 1) * (hi_w - lo_w + 1));
            float4 a = make_float4(0.f, 0.f, 0.f, 0.f);
            int base = (r * 26 + q) * 8 + coff;
            #pragma unroll
            for (int j = 0; j < 6; ++j) {
                float4 v = *(const float4*)&rs[base + j * 8];
                a.x += v.x; a.y += v.y; a.z += v.z; a.w += v.w;
            }
            float4 xv = *(const float4*)&xs[((r + 2) * 26 + (q + 2)) * 8 + coff];
            d.x = fabsf(xv.x - a.x * inv_cnt);
            d.y = fabsf(xv.y - a.y * inv_cnt);
            d.z = fabsf(xv.z - a.z * inv_cnt);
            d.w = fabsf(xv.w - a.w * inv_cnt);
        }
        *(float4*)&lmd[(r * 21 + q) * 8 + coff] = d;
    }
    __syncthreads();

    // Phase 4: vertical 6-sums of d
    for (int p = pix; p < 336; p += 128) {
        int r = p / 21, q = p - r * 21;
        float4 a = make_float4(0.f, 0.f, 0.f, 0.f);
        int base = (r * 21 + q) * 8 + coff;
        #pragma unroll
        for (int j = 0; j < 6; ++j) {
            float4 v = *(const float4*)&lmd[base + j * (21 * 8)];
            a.x += v.x; a.y += v.y; a.z += v.z; a.w += v.w;
        }
        *(float4*)&rsd[(r * 21 + q) * 8 + coff] = a;
    }
    __syncthreads();

    // Phase 5: horizontal 6-sums + blend + write
    for (int p = pix; p < 256; p += 128) {
        int ho = p >> 4, wo = p & 15;
        int h = h0 + ho, w = w0 + wo;
        int lo_h = max(h - 2, 0), hi_h = min(h + 3, 127);
        int lo_w = max(w - 2, 0), hi_w = min(w + 3, 127);
        float inv_cnt = 1.0f / (float)((hi_h - lo_h + 1) * (hi_w - lo_w + 1));

        float4 ms = make_float4(0.f, 0.f, 0.f, 0.f);   // box-sum of d
        float4 ls = make_float4(0.f, 0.f, 0.f, 0.f);   // box-sum of x
        int bm = (ho * 21 + wo) * 8 + coff;
        int bl = ((ho + 2) * 26 + (wo + 2)) * 8 + coff;
        #pragma unroll
        for (int j = 0; j < 6; ++j) {
            float4 a = *(const float4*)&rsd[bm + j * 8];
            ms.x += a.x; ms.y += a.y; ms.z += a.z; ms.w += a.w;
            float4 b = *(const float4*)&rs[bl + j * 8];
            ls.x += b.x; ls.y += b.y; ls.z += b.z; ls.w += b.w;
        }
        float4 xv = *(const float4*)&xs[((ho + 4) * 26 + (wo + 4)) * 8 + coff];

        float4 o;
        float* po = &o.x;
        const float* pm = &ms.x;
        const float* pl = &ls.x;
        const float* px = &xv.x;
        #pragma unroll
        for (int k = 0; k < 4; ++k) {
            int cc = coff + k;
            float lm  = pl[k] * inv_cnt;
            float mad = pm[k] * inv_cnt;
            float xl  = (px[k] - lm) / (mad + EPS);
            float xb  = (px[k] - prm[cc]) * prm[8 + cc];
            float wgt = prm[16 + cc];
            float r   = wgt * xl + (1.0f - wgt) * xb;
            po[k] = r * prm[24 + cc] + prm[32 + cc];
        }
        *(float4*)&out[(((n * HH + h) * WW + w) * CC) + c0 + coff] = o;
    }
}

extern "C" void kernel_launch(void* const* d_in, const int* in_sizes, int n_in,
                              void* d_out, int out_size, void* d_ws, size_t ws_size,
                              hipStream_t stream) {
    const float* x     = (const float*)d_in[0];
    const float* gamma = (const float*)d_in[1];
    const float* beta  = (const float*)d_in[2];
    const float* lbw   = (const float*)d_in[3];
    float* out  = (float*)d_out;
    float* sums  = (float*)d_ws;        // [128]
    float* asums = sums + 128;          // [128]

    hipMemsetAsync(d_ws, 0, 256 * sizeof(float), stream);

    const int n4 = BN * HH * WW * CC / 4;   // 16,777,216 float4
    k_sum<<<2048, 256, 0, stream>>>(x, sums, n4);
    k_abssum<<<2048, 256, 0, stream>>>(x, sums, asums, n4);

    dim3 g3(16 * 64, BN);   // (c-chunk fastest x 64 tiles, batch)
    k_fused<<<g3, 256, 0, stream>>>(x, sums, asums, gamma, beta, lbw, out);
}

// Round 2
// 800.565 us; speedup vs baseline: 1.1980x; 1.1980x over previous
//
#include <hip/hip_runtime.h>

#define EPS 1e-5f
#define ROWS 16384    // floats per h-row (128 w * 128 c)
#define IMG  2097152  // floats per image (128*128*128)
#define N4   16777216 // total float4 count

__device__ __forceinline__ float4 f4add(float4 a, float4 b) {
    return make_float4(a.x + b.x, a.y + b.y, a.z + b.z, a.w + b.w);
}

__device__ __forceinline__ float4 ldrow(const float* xp, int r) {
    if ((unsigned)r < 128u) return *(const float4*)(xp + (long)r * ROWS);
    return make_float4(0.f, 0.f, 0.f, 0.f);
}

// ---------------- Kernel 1: per-channel partial sums (no global atomics) ----
__global__ __launch_bounds__(256) void k_sum_part(const float* __restrict__ x,
                                                  float* __restrict__ part) {
    __shared__ float s[128];
    int t = threadIdx.x;
    if (t < 128) s[t] = 0.f;
    __syncthreads();
    int tid = blockIdx.x * 256 + t;
    int stride = gridDim.x * 256;
    const float4* x4 = (const float4*)x;
    float a0 = 0.f, a1 = 0.f, a2 = 0.f, a3 = 0.f;
    for (int i = tid; i < N4; i += stride) {
        float4 v = x4[i];
        a0 += v.x; a1 += v.y; a2 += v.z; a3 += v.w;
    }
    int c4 = (tid * 4) & 127;
    atomicAdd(&s[c4 + 0], a0);
    atomicAdd(&s[c4 + 1], a1);
    atomicAdd(&s[c4 + 2], a2);
    atomicAdd(&s[c4 + 3], a3);
    __syncthreads();
    if (t < 128) part[blockIdx.x * 128 + t] = s[t];
}

// ---------------- Kernel 2: partial sums of |x - mean| ----------------------
__global__ __launch_bounds__(256) void k_abs_part(const float* __restrict__ x,
                                                  const float* __restrict__ meanv,
                                                  float* __restrict__ part) {
    __shared__ float s[128];
    int t = threadIdx.x;
    if (t < 128) s[t] = 0.f;
    __syncthreads();
    int tid = blockIdx.x * 256 + t;
    int stride = gridDim.x * 256;
    int c4 = (tid * 4) & 127;
    float m0 = meanv[c4 + 0], m1 = meanv[c4 + 1];
    float m2 = meanv[c4 + 2], m3 = meanv[c4 + 3];
    const float4* x4 = (const float4*)x;
    float a0 = 0.f, a1 = 0.f, a2 = 0.f, a3 = 0.f;
    for (int i = tid; i < N4; i += stride) {
        float4 v = x4[i];
        a0 += fabsf(v.x - m0); a1 += fabsf(v.y - m1);
        a2 += fabsf(v.z - m2); a3 += fabsf(v.w - m3);
    }
    atomicAdd(&s[c4 + 0], a0);
    atomicAdd(&s[c4 + 1], a1);
    atomicAdd(&s[c4 + 2], a2);
    atomicAdd(&s[c4 + 3], a3);
    __syncthreads();
    if (t < 128) part[blockIdx.x * 128 + t] = s[t];
}

// ---------------- tiny final reduce: mode 0 -> mean, mode 1 -> 1/(sigma+eps)
__global__ __launch_bounds__(128) void k_reduce(const float* __restrict__ part,
                                                int nb, float* __restrict__ dst,
                                                int mode) {
    int c = threadIdx.x;
    float a = 0.f;
    #pragma unroll 8
    for (int b = 0; b < nb; ++b) a += part[b * 128 + c];
    float m = a * (1.0f / 524288.0f);
    dst[c] = mode ? 1.0f / (m + EPS) : m;
}

// ---------------- Kernel 3: fused, column-sliding-window --------------------
// Block: full W(=128) x 8-channel chunk x 64-row strip. 256 thr = 128 w x 2 c-halves.
// Register rings do vertical 6-sums; LDS holds one row of vertical sums for the
// horizontal exchange (double-buffered, +2/+4 padded slots so the 6-tap
// horizontal read is unconditional b128 with immediate offsets).
__global__ __launch_bounds__(256, 4) void k_fused(
    const float* __restrict__ x,
    const float* __restrict__ meanv, const float* __restrict__ isigv,
    const float* __restrict__ gamma, const float* __restrict__ beta,
    const float* __restrict__ lbw, float* __restrict__ out) {
    __shared__ __align__(16) float A[2][134 * 8];
    __shared__ __align__(16) float B[2][134 * 8];

    const int t = threadIdx.x;
    const int w = t >> 1;
    const int coff = (t & 1) * 4;
    const int c0 = (blockIdx.x & 15) * 8;   // channel chunk fastest -> line sharing
    const int h0 = (blockIdx.x >> 4) * 64;  // row strip
    const int n = blockIdx.y;

    // zero the pad slots (slot indices 0,1,130..133 in each of 4 buffers)
    if (t < 192) {
        int buf = t / 48, r = t % 48;
        int slot = r >> 3;
        slot = (slot < 2) ? slot : slot + 128;
        float* p = (buf & 2) ? B[buf & 1] : A[buf & 1];
        p[slot * 8 + (r & 7)] = 0.f;
    }

    const float* xp = x + (long)n * IMG + (long)w * 128 + (c0 + coff);
    float*       op = out + (long)n * IMG + (long)w * 128 + (c0 + coff);

    const int cc = c0 + coff;
    const float4 bm = *(const float4*)&meanv[cc];
    const float4 bs = *(const float4*)&isigv[cc];
    const float4 wb = *(const float4*)&lbw[cc];
    const float4 gm = *(const float4*)&gamma[cc];
    const float4 bt = *(const float4*)&beta[cc];

    const int lo_w = max(w - 2, 0), hi_w = min(w + 3, 127);
    const float cw = (float)(hi_w - lo_w + 1);

    // x ring: rows q-3 .. q+3 (xr0..xr6). Preload rows h0-5..h0 into xr1..xr6.
    float4 xr1 = ldrow(xp, h0 - 5), xr2 = ldrow(xp, h0 - 4), xr3 = ldrow(xp, h0 - 3);
    float4 xr4 = ldrow(xp, h0 - 2), xr5 = ldrow(xp, h0 - 1), xr6 = ldrow(xp, h0);

    const float4 z4 = make_float4(0.f, 0.f, 0.f, 0.f);
    float4 dr0 = z4, dr1 = z4, dr2 = z4, dr3 = z4, dr4 = z4, dr5 = z4; // |x-lm| ring
    float4 er0 = z4, er1 = z4, er2 = z4, er3 = z4;                     // signed x-lm ring

    for (int q = h0 - 2; q <= h0 + 66; ++q) {
        // advance x ring, load row q+3
        float4 xr0 = xr1;
        xr1 = xr2; xr2 = xr3; xr3 = xr4; xr4 = xr5; xr5 = xr6;
        xr6 = ldrow(xp, q + 3);

        // vertical 6-sum of x for row q (rows q-2..q+3)
        float4 vx = f4add(f4add(f4add(xr1, xr2), f4add(xr3, xr4)), f4add(xr5, xr6));
        float* As = A[q & 1];
        *(float4*)&As[(w + 2) * 8 + coff] = vx;
        __syncthreads();

        // horizontal 6-sum (pads are zero, counts handled analytically)
        const float* Ab = &As[w * 8 + coff];
        float4 ha = *(const float4*)(Ab + 0);
        ha = f4add(ha, *(const float4*)(Ab + 8));
        ha = f4add(ha, *(const float4*)(Ab + 16));
        ha = f4add(ha, *(const float4*)(Ab + 24));
        ha = f4add(ha, *(const float4*)(Ab + 32));
        ha = f4add(ha, *(const float4*)(Ab + 40));

        // deviation field at row q
        float4 dd = z4, ee = z4;
        if ((unsigned)q < 128u) {
            int lo_h = max(q - 2, 0), hi_h = min(q + 3, 127);
            float inv = 1.0f / ((float)(hi_h - lo_h + 1) * cw);
            ee.x = xr3.x - ha.x * inv;
            ee.y = xr3.y - ha.y * inv;
            ee.z = xr3.z - ha.z * inv;
            ee.w = xr3.w - ha.w * inv;
            dd.x = fabsf(ee.x); dd.y = fabsf(ee.y);
            dd.z = fabsf(ee.z); dd.w = fabsf(ee.w);
        }
        er0 = er1; er1 = er2; er2 = er3; er3 = ee;
        dr0 = dr1; dr1 = dr2; dr2 = dr3; dr3 = dr4; dr4 = dr5; dr5 = dd;

        // vertical 6-sum of deviations for output row h = q-3
        float4 vd = f4add(f4add(f4add(dr0, dr1), f4add(dr2, dr3)), f4add(dr4, dr5));
        float* Bs = B[q & 1];
        *(float4*)&Bs[(w + 2) * 8 + coff] = vd;
        __syncthreads();

        int h = q - 3;
        if (h >= h0) {  // h <= h0+63 guaranteed by loop bound
            const float* Bb = &Bs[w * 8 + coff];
            float4 hb = *(const float4*)(Bb + 0);
            hb = f4add(hb, *(const float4*)(Bb + 8));
            hb = f4add(hb, *(const float4*)(Bb + 16));
            hb = f4add(hb, *(const float4*)(Bb + 24));
            hb = f4add(hb, *(const float4*)(Bb + 32));
            hb = f4add(hb, *(const float4*)(Bb + 40));

            int lo_h = max(h - 2, 0), hi_h = min(h + 3, 127);
            float inv = 1.0f / ((float)(hi_h - lo_h + 1) * cw);

            float4 o;
            {
                float mad = hb.x * inv;
                float xl = er0.x / (mad + EPS);
                float xb = (xr0.x - bm.x) * bs.x;
                o.x = (wb.x * xl + (1.0f - wb.x) * xb) * gm.x + bt.x;
            }
            {
                float mad = hb.y * inv;
                float xl = er0.y / (mad + EPS);
                float xb = (xr0.y - bm.y) * bs.y;
                o.y = (wb.y * xl + (1.0f - wb.y) * xb) * gm.y + bt.y;
            }
            {
                float mad = hb.z * inv;
                float xl = er0.z / (mad + EPS);
                float xb = (xr0.z - bm.z) * bs.z;
                o.z = (wb.z * xl + (1.0f - wb.z) * xb) * gm.z + bt.z;
            }
            {
                float mad = hb.w * inv;
                float xl = er0.w / (mad + EPS);
                float xb = (xr0.w - bm.w) * bs.w;
                o.w = (wb.w * xl + (1.0f - wb.w) * xb) * gm.w + bt.w;
            }
            *(float4*)(op + (long)h * ROWS) = o;
        }
    }
}

extern "C" void kernel_launch(void* const* d_in, const int* in_sizes, int n_in,
                              void* d_out, int out_size, void* d_ws, size_t ws_size,
                              hipStream_t stream) {
    const float* x     = (const float*)d_in[0];
    const float* gamma = (const float*)d_in[1];
    const float* beta  = (const float*)d_in[2];
    const float* lbw   = (const float*)d_in[3];
    float* out = (float*)d_out;

    float* part  = (float*)d_ws;        // [1024][128]
    float* meanv = part + 131072;       // [128]
    float* isigv = meanv + 128;         // [128]

    k_sum_part<<<1024, 256, 0, stream>>>(x, part);
    k_reduce<<<1, 128, 0, stream>>>(part, 1024, meanv, 0);
    k_abs_part<<<1024, 256, 0, stream>>>(x, meanv, part);
    k_reduce<<<1, 128, 0, stream>>>(part, 1024, isigv, 1);

    dim3 g3(32, 32);  // (16 c-chunks x 2 row-strips, batch)
    k_fused<<<g3, 256, 0, stream>>>(x, meanv, isigv, gamma, beta, lbw, out);
}